// Round 9
// baseline (555.554 us; speedup 1.0000x reference)
//
#include <hip/hip_runtime.h>

// CRF log-likelihood: B=512, T=1024, K=64. out = mean_b(Z[b]-gold[b]).
//
// fwd2_kernel: 2 sequences per wave (grid 256, 1 block/CU, all co-resident;
// wall clock = slowest block = max sequence length).
// Exp-space recurrence:
//   w_{t+1} = (E w_t) o e^{h_t} * rc_t,  E = exp(trans) in 64 VGPR/lane,
// rc_t = rcp(w_t[REFL]) from the PRE-write state, folded into m = e^h * rc
// during the LDS write->read latency window. Critical path per step:
// ds_write -> 16x broadcast ds_read_b128 -> 32 v_pk_fma_f32 -> tree -> 1 mul.
// Seq B's reads/FMAs overlap seq A's LDS round-trip (single-wave in-order DS).
// O accumulates -log(rc) in f64 on a side chain (exact bookkeeping: logs the
// factor actually applied, so rcp rounding cancels).
// Lockstep to min(len0,len1); uniform-branch single-seq tail to max len.

#define PAD_IDX 0
#define SOS_IDX 1
#define EOS_IDX 2
constexpr int B = 512, T = 1024, K = 64;
constexpr int REFL = 3;   // renorm ref lane: first live state (0..2 dead/special)

typedef float v2f __attribute__((ext_vector_type(2)));

// y0 may be int64 (reference dtype) or int32 (JAX x64-off). Little-endian:
// y0[1]==0 iff int64 (hi word of SOS); int32 data has y0[1]>=3.
__device__ __forceinline__ int yval(const int* __restrict__ y, int i, int sh) {
  return y[i << sh];
}

__global__ __launch_bounds__(1024) void gold_len_kernel(
    const float* __restrict__ h, const float* __restrict__ trans,
    const int* __restrict__ y0, double* __restrict__ goldOut,
    int* __restrict__ lenOut)
{
  const int b = blockIdx.x, tid = threadIdx.x;      // tid == t
  const float* hb = h + (size_t)b * T * K;
  const int sh = (y0[1] == 0) ? 1 : 0;
  const int* yb = y0 + (((size_t)b * (T + 1)) << sh);

  int ycur = yval(yb, tid + 1, sh);
  double acc = 0.0;
  int mpos = 0;
  if (ycur > PAD_IDX) {                             // pads are a suffix
    int yprev = yval(yb, tid, sh);
    acc = (double)(hb[(size_t)tid * K + ycur] + trans[ycur * K + yprev]);
    mpos = tid + 1;
  }
  #pragma unroll
  for (int off = 32; off > 0; off >>= 1) {
    acc += __shfl_down(acc, off, 64);
    mpos = max(mpos, __shfl_down(mpos, off, 64));
  }
  __shared__ double sa[16];
  __shared__ int sm[16];
  if ((tid & 63) == 0) { sa[tid >> 6] = acc; sm[tid >> 6] = mpos; }
  __syncthreads();
  if (tid < 64) {
    double a = (tid < 16) ? sa[tid] : 0.0;
    int mp = (tid < 16) ? sm[tid] : 0;
    #pragma unroll
    for (int off = 8; off > 0; off >>= 1) {
      a += __shfl_down(a, off, 64);
      mp = max(mp, __shfl_down(mp, off, 64));
    }
    if (tid == 0) {
      int last = yval(yb, mp, sh);                  // last real token
      goldOut[b] = a + (double)trans[EOS_IDX * K + last];
      lenOut[b] = mp;
    }
  }
}

__global__ __launch_bounds__(64) void fwd2_kernel(
    const float* __restrict__ h, const float* __restrict__ trans,
    const int* __restrict__ lenIn, double* __restrict__ ZdOut)
{
  __shared__ alignas(16) float lds0[K];
  __shared__ alignas(16) float lds1[K];
  const int k = threadIdx.x;                        // lane = state
  const int b0 = 2 * blockIdx.x, b1 = b0 + 1;
  const float* hb0 = h + (size_t)b0 * T * K;
  const float* hb1 = h + (size_t)b1 * T * K;
  const int len0 = lenIn[b0], len1 = lenIn[b1];

  // E row k as 32 float2 (static idx -> VGPRs); exp(-10000)=0 reproduces masking.
  v2f E2[32];
  #pragma unroll
  for (int j = 0; j < 32; ++j) {
    E2[j].x = __expf(trans[k * K + 2 * j]);
    E2[j].y = __expf(trans[k * K + 2 * j + 1]);
  }
  const float eEOS = __expf(trans[EOS_IDX * K + k]);

  float w0 = (k == SOS_IDX) ? 1.0f : 0.0f, w1 = w0; // exp-space states (scaled)
  double O0 = 0.0, O1 = 0.0;                        // f64 log-offsets (side chain)

  // Renorm factor from PRE-write state (off critical path). Guard t=0 (w[3]=0).
  auto RC = [&](float w) {
    float wr = __uint_as_float(__builtin_amdgcn_readlane(__float_as_uint(w), REFL));
    return wr > 0.0f ? __builtin_amdgcn_rcpf(wr) : 1.0f;
  };

  auto STEP2 = [&](float f0, float f1) {            // one step, both sequences
    lds0[k] = w0;                                   // stores first: latency window
    lds1[k] = w1;                                   // covers rc/m/O VALU work
    float rc0 = RC(w0), rc1 = RC(w1);
    float m0 = f0 * rc0, m1 = f1 * rc1;
    O0 -= (double)__logf(rc0);
    O1 -= (double)__logf(rc1);
    const float4* u0 = reinterpret_cast<const float4*>(lds0);
    const float4* u1 = reinterpret_cast<const float4*>(lds1);
    v2f p0 = {0,0}, p1 = {0,0}, p2 = {0,0}, p3 = {0,0};
    v2f q0 = {0,0}, q1 = {0,0}, q2 = {0,0}, q3 = {0,0};
    #pragma unroll
    for (int c = 0; c < 16; ++c) {                  // broadcast reads, pk FMAs
      float4 x0 = u0[c];
      float4 x1 = u1[c];
      v2f xa0 = {x0.x, x0.y}, xb0 = {x0.z, x0.w};
      v2f xa1 = {x1.x, x1.y}, xb1 = {x1.z, x1.w};
      if (c & 1) {
        p2 = E2[2*c] * xa0 + p2;  p3 = E2[2*c+1] * xb0 + p3;
        q2 = E2[2*c] * xa1 + q2;  q3 = E2[2*c+1] * xb1 + q3;
      } else {
        p0 = E2[2*c] * xa0 + p0;  p1 = E2[2*c+1] * xb0 + p1;
        q0 = E2[2*c] * xa1 + q0;  q1 = E2[2*c+1] * xb1 + q1;
      }
    }
    v2f sp = (p0 + p2) + (p1 + p3);
    v2f sq = (q0 + q2) + (q1 + q3);
    w0 = (sp.x + sp.y) * m0;                        // one mul on critical path
    w1 = (sq.x + sq.y) * m1;
  };

  auto STEP1 = [&](float f, float& w, double& O) {  // tail: single sequence
    lds0[k] = w;
    float rc = RC(w);
    float m = f * rc;
    O -= (double)__logf(rc);
    const float4* u0 = reinterpret_cast<const float4*>(lds0);
    v2f p0 = {0,0}, p1 = {0,0}, p2 = {0,0}, p3 = {0,0};
    #pragma unroll
    for (int c = 0; c < 16; ++c) {
      float4 x0 = u0[c];
      v2f xa0 = {x0.x, x0.y}, xb0 = {x0.z, x0.w};
      if (c & 1) { p2 = E2[2*c] * xa0 + p2;  p3 = E2[2*c+1] * xb0 + p3; }
      else       { p0 = E2[2*c] * xa0 + p0;  p1 = E2[2*c+1] * xb0 + p1; }
    }
    v2f sp = (p0 + p2) + (p1 + p3);
    w = (sp.x + sp.y) * m;
  };

  auto EPI = [&](float w, double O, int b) {        // Z = O + log(sum w*eEOS)
    float s = w * eEOS;
    #pragma unroll
    for (int off = 32; off > 0; off >>= 1) s += __shfl_xor(s, off, 64);
    if (k == 0) ZdOut[b] = O + (double)__logf(s);
  };

  const int lmin = min(len0, len1), lmax = max(len0, len1);
  const int lm1_0 = len0 - 1, lm1_1 = len1 - 1;
  auto hl0 = [&](int t) { return hb0[(size_t)min(t, lm1_0) * K + k]; };
  auto hl1 = [&](int t) { return hb1[(size_t)min(t, lm1_1) * K + k]; };

  // Lockstep phase with 4-deep prefetch for both sequences.
  float p00 = hl0(0), p01 = hl0(1), p02 = hl0(2), p03 = hl0(3);
  float p10 = hl1(0), p11 = hl1(1), p12 = hl1(2), p13 = hl1(3);
  int t = 0;
  for (; t + 4 <= lmin; t += 4) {
    float n00 = hl0(t+4), n01 = hl0(t+5), n02 = hl0(t+6), n03 = hl0(t+7);
    float n10 = hl1(t+4), n11 = hl1(t+5), n12 = hl1(t+6), n13 = hl1(t+7);
    STEP2(__expf(p00), __expf(p10));
    STEP2(__expf(p01), __expf(p11));
    STEP2(__expf(p02), __expf(p12));
    STEP2(__expf(p03), __expf(p13));
    p00 = n00; p01 = n01; p02 = n02; p03 = n03;
    p10 = n10; p11 = n11; p12 = n12; p13 = n13;
  }
  for (; t < lmin; ++t) STEP2(__expf(hl0(t)), __expf(hl1(t)));

  // Finish the shorter sequence; continue the longer (wave-uniform select).
  const bool sel0long = (len0 >= len1);
  if (sel0long) EPI(w1, O1, b1); else EPI(w0, O0, b0);

  const float* hbL = sel0long ? hb0 : hb1;
  const int lenL = lmax, lm1L = lenL - 1;
  float wL = sel0long ? w0 : w1;
  double OL = sel0long ? O0 : O1;
  auto hlL = [&](int tt) { return hbL[(size_t)min(tt, lm1L) * K + k]; };

  float q0 = hlL(t), q1 = hlL(t + 1), q2 = hlL(t + 2), q3 = hlL(t + 3);
  for (; t + 4 <= lenL; t += 4) {
    float n0 = hlL(t+4), n1 = hlL(t+5), n2 = hlL(t+6), n3 = hlL(t+7);
    STEP1(__expf(q0), wL, OL);
    STEP1(__expf(q1), wL, OL);
    STEP1(__expf(q2), wL, OL);
    STEP1(__expf(q3), wL, OL);
    q0 = n0; q1 = n1; q2 = n2; q3 = n3;
  }
  for (; t < lenL; ++t) STEP1(__expf(hlL(t)), wL, OL);
  EPI(wL, OL, sel0long ? b0 : b1);
}

__global__ __launch_bounds__(512) void reduce_kernel(
    const double* __restrict__ Zd, const double* __restrict__ goldIn,
    float* __restrict__ out)
{
  __shared__ double sdata[8];
  const int tid = threadIdx.x;
  double v = Zd[tid] - goldIn[tid];
  #pragma unroll
  for (int off = 32; off > 0; off >>= 1) v += __shfl_down(v, off, 64);
  if ((tid & 63) == 0) sdata[tid >> 6] = v;
  __syncthreads();
  if (tid == 0) {
    double s = 0.0;
    #pragma unroll
    for (int i = 0; i < 8; ++i) s += sdata[i];
    out[0] = (float)(s / (double)B);
  }
}

extern "C" void kernel_launch(void* const* d_in, const int* in_sizes, int n_in,
                              void* d_out, int out_size, void* d_ws, size_t ws_size,
                              hipStream_t stream) {
  const float* h = (const float*)d_in[0];
  const float* trans = (const float*)d_in[1];
  const int* y0 = (const int*)d_in[2];   // int32 or int64; detected in-kernel

  double* Zd = (double*)d_ws;            // [B]
  double* gold = Zd + B;                 // [B]
  int* len = (int*)(gold + B);           // [B]

  gold_len_kernel<<<B, 1024, 0, stream>>>(h, trans, y0, gold, len);
  fwd2_kernel<<<B / 2, 64, 0, stream>>>(h, trans, len, Zd);
  reduce_kernel<<<1, 512, 0, stream>>>(Zd, gold, (float*)d_out);
}